// Round 3
// baseline (59331.305 us; speedup 1.0000x reference)
//
#include <hip/hip_runtime.h>

// ContinuousGRULayer round 3: f16 weights + v_dot2_f32_f16, M=2 chains/WG.
//   64 WGs x 1024 threads. Each WG runs batch rows {2b, 2b+1} sharing every
//   weight load (halves L2 traffic); dot2 quarters VALU ops vs unpack+fma.
//   Thread (j, half): half0 = z-gate + g-lowK + RK4 commit for both chains;
//   half1 = r-gate + rh + g-highK for both chains. 3 barriers per RK4 stage.

namespace {
constexpr int kB = 128, kT = 512, kF = 128, kH = 512, kFH = 640;
// d_ws layout in uint4 (16B = 8 f16) units: slice p of neuron j at
// [region + p*kH + j] -> lane j reads 16B, wave-coalesced 1KB.
constexpr int XS = (kF / 8) * kH;          // 8192 per x-gate
constexpr int HS = (kH / 8) * kH;          // 32768 per h-gate
constexpr int OXZ = 0, OXR = XS, OXG = 2 * XS;
constexpr int OHZ = 3 * XS, OHR = 3 * XS + HS, OHG = 3 * XS + 2 * HS;
constexpr int OTOT = 3 * XS + 3 * HS;      // 122880 * 16B = 1.97 MB
}  // namespace

typedef _Float16 h2_t __attribute__((ext_vector_type(2)));

__device__ __forceinline__ unsigned short f2h(float f) {
  return __builtin_bit_cast(unsigned short, (_Float16)f);   // RNE convert
}
__device__ __forceinline__ unsigned pack2h(float a, float b) {
  return (unsigned)f2h(a) | ((unsigned)f2h(b) << 16);
}
__device__ __forceinline__ float h2f(unsigned short u) {
  return (float)__builtin_bit_cast(_Float16, u);
}
__device__ __forceinline__ float dot2(unsigned w, unsigned h, float acc) {
  return __builtin_amdgcn_fdot2(__builtin_bit_cast(h2_t, w),
                                __builtin_bit_cast(h2_t, h), acc, false);
}

// ---- weight pre-pack: f32 [H][F+H] -> f16 k8-transposed regions in d_ws ----
__global__ void convert_weights(const float* __restrict__ Wz,
                                const float* __restrict__ Wr,
                                const float* __restrict__ Wg,
                                uint4* __restrict__ ws) {
  int tid = blockIdx.x * 256 + threadIdx.x;
  if (tid >= OTOT) return;
  const float* W;
  int cbase, p, j;
  if (tid < 3 * XS) {
    int m = tid / XS, l = tid - m * XS;
    W = (m == 0) ? Wz : (m == 1) ? Wr : Wg;
    cbase = 0; p = l / kH; j = l - p * kH;
  } else {
    int t2 = tid - 3 * XS;
    int m = t2 / HS, l = t2 - m * HS;
    W = (m == 0) ? Wz : (m == 1) ? Wr : Wg;
    cbase = kF; p = l / kH; j = l - p * kH;
  }
  const float* s = W + j * kFH + cbase + p * 8;
  uint4 o;
  o.x = pack2h(s[0], s[1]); o.y = pack2h(s[2], s[3]);
  o.z = pack2h(s[4], s[5]); o.w = pack2h(s[6], s[7]);
  ws[tid] = o;
}

// N slices of 8 K-elems, two chains sharing each weight load.
// wp pre-offset by j; h0/h1 are k-packed f16 LDS arrays (uint units).
template <int N>
__device__ __forceinline__ void dot2ch(const uint4* __restrict__ wp,
                                       const unsigned* __restrict__ h0,
                                       const unsigned* __restrict__ h1,
                                       float& a0, float& a1) {
#pragma unroll 8
  for (int p = 0; p < N; ++p) {
    const uint4 w = wp[p * kH];
    const uint4 u = *reinterpret_cast<const uint4*>(h0 + p * 4);
    const uint4 v = *reinterpret_cast<const uint4*>(h1 + p * 4);
    a0 = dot2(w.x, u.x, a0); a0 = dot2(w.y, u.y, a0);
    a0 = dot2(w.z, u.z, a0); a0 = dot2(w.w, u.w, a0);
    a1 = dot2(w.x, v.x, a1); a1 = dot2(w.y, v.y, a1);
    a1 = dot2(w.z, v.z, a1); a1 = dot2(w.w, v.w, a1);
  }
}

__global__ __launch_bounds__(1024, 4) void cgru_scan2(
    const float* __restrict__ x, const float* __restrict__ td,
    const float* __restrict__ bz, const float* __restrict__ br,
    const float* __restrict__ bg, const uint4* __restrict__ ws,
    float* __restrict__ out) {
  __shared__ __align__(16) unsigned hpk[2][kH / 2];   // stage h, k-packed f16
  __shared__ __align__(16) unsigned rpk[2][kH / 2];   // r*h, k-packed f16
  __shared__ __align__(16) unsigned xpk[2][kF / 2];   // x_t, k-packed f16
  __shared__ __align__(16) float gpart[2][kH];        // half1's g partials

  const int tid = threadIdx.x;
  const int j = tid & (kH - 1);
  const int half = tid >> 9;
  const int b0 = blockIdx.x * 2;

  const uint4* __restrict__ wxz = ws + OXZ + j;
  const uint4* __restrict__ wxr = ws + OXR + j;
  const uint4* __restrict__ wxg = ws + OXG + j;
  const uint4* __restrict__ whz = ws + OHZ + j;
  const uint4* __restrict__ whr = ws + OHR + j;
  const uint4* __restrict__ whg = ws + OHG + j;

  const float bzv = bz[j], brv = br[j], bgv = bg[j];

  float hb0 = 0.f, hb1 = 0.f;   // committed h (half0)
  float hs0 = 0.f, hs1 = 0.f;   // stage-input h[j] (half0)
  if (tid < kH) ((unsigned*)hpk)[tid] = 0;   // h=0, both chains

  for (int t = 0; t < kT; ++t) {
    if (tid < kF) {   // x_t for both chains, k-packed f16
      const int c = tid >> 6, q = tid & 63;
      const float2 xv = *reinterpret_cast<const float2*>(
          x + ((b0 + c) * kT + t) * kF + 2 * q);
      xpk[c][q] = pack2h(xv.x, xv.y);
    }
    __syncthreads();   // xt (+ initial h) visible

    // ---- x-part + bias, reused by all 8 RK4 evals of this timestep ----
    float az0, az1, ar0 = 0.f, ar1 = 0.f, ag0, ag1;
    if (half == 0) {
      az0 = bzv; az1 = bzv;
      dot2ch<kF / 8>(wxz, xpk[0], xpk[1], az0, az1);
      ag0 = bgv; ag1 = bgv;
      dot2ch<kF / 16>(wxg, xpk[0], xpk[1], ag0, ag1);
    } else {
      ar0 = brv; ar1 = brv;
      dot2ch<kF / 8>(wxr, xpk[0], xpk[1], ar0, ar1);
      ag0 = 0.f; ag1 = 0.f;
      dot2ch<kF / 16>(wxg + (kF / 16) * kH, xpk[0] + kF / 4, xpk[1] + kF / 4,
                      ag0, ag1);
      az0 = az1 = 0.f;
    }
    const float dt0 = fminf(td[(b0 + 0) * kT + t], 1.0f) * 0.5f;
    const float dt1 = fminf(td[(b0 + 1) * kT + t], 1.0f) * 0.5f;

    float ka0 = 0.f, ka1 = 0.f;
    for (int e = 0; e < 8; ++e) {   // 2 ODE steps x 4 RK4 stages
      const int s = e & 3;
      if (s == 0) { ka0 = 0.f; ka1 = 0.f; }

      float z0 = 0.f, z1 = 0.f;
      if (half == 0) {
        float za0 = az0, za1 = az1;
        dot2ch<kH / 8>(whz, hpk[0], hpk[1], za0, za1);
        z0 = 1.0f / (1.0f + __expf(-za0));
        z1 = 1.0f / (1.0f + __expf(-za1));
      } else {
        float ra0 = ar0, ra1 = ar1;
        dot2ch<kH / 8>(whr, hpk[0], hpk[1], ra0, ra1);
        const float r0 = 1.0f / (1.0f + __expf(-ra0));
        const float r1 = 1.0f / (1.0f + __expf(-ra1));
        const float h0 = h2f(((const unsigned short*)hpk[0])[j]);
        const float h1 = h2f(((const unsigned short*)hpk[1])[j]);
        ((unsigned short*)rpk[0])[j] = f2h(r0 * h0);
        ((unsigned short*)rpk[1])[j] = f2h(r1 * h1);
      }
      __syncthreads();   // #1: rh visible; hpk reads done

      // ---- g dot: each half does its K-half for both chains ----
      float gp0, gp1;
      {
        const uint4* wg = whg + half * (kH / 16) * kH;
        const unsigned* r0p = rpk[0] + half * (kH / 4);
        const unsigned* r1p = rpk[1] + half * (kH / 4);
        gp0 = ag0; gp1 = ag1;
        dot2ch<kH / 16>(wg, r0p, r1p, gp0, gp1);
      }
      if (half == 1) { gpart[0][j] = gp0; gpart[1][j] = gp1; }
      __syncthreads();   // #2: gpart visible

      if (half == 0) {
        const float g0 = tanhf(gp0 + gpart[0][j]);
        const float g1 = tanhf(gp1 + gpart[1][j]);
        const float k0 = (1.0f - z0) * (g0 - hs0);
        const float k1 = (1.0f - z1) * (g1 - hs1);
        const float wgt = (s == 1 || s == 2) ? 2.0f : 1.0f;
        ka0 += wgt * k0; ka1 += wgt * k1;
        float n0, n1;
        if (s < 3) {
          const float f = (s == 2) ? 1.0f : 0.5f;
          n0 = fmaf(f * dt0, k0, hb0);
          n1 = fmaf(f * dt1, k1, hb1);
        } else {
          hb0 = fmaf(dt0 * (1.0f / 6.0f), ka0, hb0);
          hb1 = fmaf(dt1 * (1.0f / 6.0f), ka1, hb1);
          n0 = hb0; n1 = hb1;
        }
        ((unsigned short*)hpk[0])[j] = f2h(n0);
        ((unsigned short*)hpk[1])[j] = f2h(n1);
        hs0 = n0; hs1 = n1;
      }
      __syncthreads();   // #3: new h visible
    }

    if (half == 0) {   // coalesced f32 stores, both chains
      out[((b0 + 0) * kT + t) * kH + j] = hb0;
      out[((b0 + 1) * kT + t) * kH + j] = hb1;
    }
  }
}

extern "C" void kernel_launch(void* const* d_in, const int* in_sizes, int n_in,
                              void* d_out, int out_size, void* d_ws, size_t ws_size,
                              hipStream_t stream) {
  const float* x  = (const float*)d_in[0];
  const float* td = (const float*)d_in[1];
  const float* Wz = (const float*)d_in[2];
  const float* bz = (const float*)d_in[3];
  const float* Wr = (const float*)d_in[4];
  const float* br = (const float*)d_in[5];
  const float* Wg = (const float*)d_in[6];
  const float* bg = (const float*)d_in[7];
  float* out = (float*)d_out;

  convert_weights<<<(OTOT + 255) / 256, 256, 0, stream>>>(
      Wz, Wr, Wg, (uint4*)d_ws);
  cgru_scan2<<<kB / 2, 1024, 0, stream>>>(
      x, td, bz, br, bg, (const uint4*)d_ws, out);
}